// Round 1
// baseline (327.685 us; speedup 1.0000x reference)
//
#include <hip/hip_runtime.h>
#include <stdint.h>

// Problem constants (from reference)
#define B_  32
#define T_  1024
#define C_  512
#define H_  1024
#define SCALE_ 32.0f   // sqrt(1024)

// Tiling
#define BM 128
#define BN 128
#define BK 32
#define ROWE 32              // elems per LDS row, no pad; XOR swizzle for banks
#define NSTEP (C_ / BK)      // 16

typedef __attribute__((ext_vector_type(8))) short frag_ab;   // 8 bf16 (4 VGPRs)
typedef __attribute__((ext_vector_type(4))) float frag_cd;   // 4 fp32

// Packed f32x2 -> bf16x2 (RNE), single instruction. Non-volatile: scheduler
// may move/CSE it freely (m240: volatile/pinned cvt_pk hurts).
__device__ __forceinline__ uint32_t cvtpk_bf16(float lo, float hi) {
    uint32_t r;
    asm("v_cvt_pk_bf16_f32 %0, %1, %2" : "=v"(r) : "v"(lo), "v"(hi));
    return r;
}

__device__ __forceinline__ void cvt4_store(unsigned short* dst, float4 v) {
    uint2 p;
    p.x = cvtpk_bf16(v.x, v.y);
    p.y = cvtpk_bf16(v.z, v.w);
    *(uint2*)dst = p;   // 8 B aligned
}

// Raw barrier WITHOUT the __syncthreads() vmcnt(0) drain: per-wave LDS drain
// (lgkmcnt) + s_barrier. Global prefetch loads (register-destined, read-only
// data) legitimately stay in flight across it. "memory" fences on both sides
// stop the compiler moving LDS ops across the barrier (m152 race lesson).
#define BARRIER() do { \
    asm volatile("s_waitcnt lgkmcnt(0)" ::: "memory"); \
    __builtin_amdgcn_s_barrier(); \
    asm volatile("" ::: "memory"); \
} while (0)

__global__ __launch_bounds__(256, 3)
void NeuralEmbeddingLayer_kernel(
    const float* __restrict__ features,     // [B,T,C]
    const int*   __restrict__ ts,           // [B,T]
    const int*   __restrict__ date_idx,     // [B]
    const float* __restrict__ spikes,       // [N_DATES,H,C]
    const float* __restrict__ spikes_bias,  // [N_DATES]
    const float* __restrict__ pos,          // [MAX_F,H]
    float*       __restrict__ out)          // [B,T,H]
{
    const int tid = threadIdx.x;
    const int bid = blockIdx.x;

    // XCD-clustered mapping: one XCD gets whole samples (A+B working set fits
    // its private 4 MB L2).
    const int xcd   = bid & 7;
    const int local = bid >> 3;               // 0..255 within this XCD
    const int b     = ((local >> 6) << 3) + xcd;  // 4 samples per XCD
    const int tile  = local & 63;
    const int t0 = (tile >> 3) * BM;
    const int h0 = (tile & 7) * BN;

    const int   date = date_idx[b];
    const float bias = spikes_bias[date];
    const float* A = features + ((size_t)b * T_ + t0) * C_;     // row stride C_
    const float* W = spikes   + ((size_t)date * H_ + h0) * C_;  // row stride C_

    __shared__ __align__(16) unsigned short ldsA[2][BM * ROWE]; // 8 KB each
    __shared__ __align__(16) unsigned short ldsB[2][BM * ROWE];
    __shared__ int lds_ts[BM];

    // ---- static per-thread staging coordinates ----
    // tile: 128 rows x 8 float4-groups; thread handles (r0 + 32*i, group jj).
    // Swizzle term is invariant in i (i*32 rows ≡ 0 mod 4 on (row>>1)&3).
    const int r0  = tid >> 3;            // 0..31
    const int c4  = (tid & 7) * 4;       // k offset in floats
    const int jj  = tid & 7;
    const int sw0 = (jj >> 1) ^ ((r0 >> 1) & 3);
    const int offBase = r0 * ROWE + sw0 * 8 + (jj & 1) * 4;

    // Two prefetch register sets: set parity = K-step parity (step s -> set s&1).
    float4 pA0[4], pB0[4], pA1[4], pB1[4];

    auto loadset = [&](float4 (&a)[4], float4 (&w)[4], int k0) {
#pragma unroll
        for (int i = 0; i < 4; ++i) {
            a[i] = *(const float4*)(A + (size_t)(r0 + 32 * i) * C_ + (k0 + c4));
            w[i] = *(const float4*)(W + (size_t)(r0 + 32 * i) * C_ + (k0 + c4));
        }
    };
    auto stageset = [&](float4 (&a)[4], float4 (&w)[4], int buf) {
#pragma unroll
        for (int i = 0; i < 4; ++i) {
            cvt4_store(&ldsA[buf][offBase + i * 1024], a[i]);
            cvt4_store(&ldsB[buf][offBase + i * 1024], w[i]);
        }
    };

    // ---- prologue: issue steps 0 and 1, stage step 0 ----
    int tsval = 0;
    if (tid < BM) tsval = ts[b * T_ + t0 + tid];
    loadset(pA0, pB0, 0);
    loadset(pA1, pB1, BK);          // stays in flight through the first barrier
    if (tid < BM) lds_ts[tid] = tsval;
    stageset(pA0, pB0, 0);          // waits only for set0 (+ts): vmcnt counted
    BARRIER();

    // ---- wave/lane decode ----
    const int wave = tid >> 6;
    const int lane = tid & 63;
    const int quad = lane >> 4;       // k-halfgroup for A/B frags; row-quad for C/D
    const int m_   = lane & 15;
    const int wm = (wave >> 1) * 64;  // wave tile origin in M (t)
    const int wn = (wave & 1) * 64;   // in N (h)

    frag_cd acc[4][4] = {};

    // ---- K loop: dbuf LDS, distance-2 register prefetch, raw barriers ----
    // Invariant at top of iter ks: LDS buf[ks&1] holds step ks;
    // set[(ks+1)&1] holds step ks+1 (in flight or arrived); set[ks&1] free.
#pragma unroll
    for (int ks = 0; ks < NSTEP; ++ks) {
        const int buf = ks & 1;

        // issue loads for step ks+2 into the freed set (parity ks&1)
        if (ks + 2 < NSTEP) {
            if ((ks & 1) == 0) loadset(pA0, pB0, (ks + 2) * BK);
            else               loadset(pA1, pB1, (ks + 2) * BK);
        }

        // B fragments up front; A fragments rolled into the MFMA loop to cap
        // fragment liveness (~20 regs) under the (256,3) register budget.
        frag_ab bfrag[4];
#pragma unroll
        for (int ni = 0; ni < 4; ++ni) {
            int row = wn + ni * 16 + m_;
            int sw  = (row >> 1) & 3;
            bfrag[ni] = *(const frag_ab*)&ldsB[buf][row * ROWE + ((quad ^ sw) * 8)];
        }
#pragma unroll
        for (int mi = 0; mi < 4; ++mi) {
            int row = wm + mi * 16 + m_;
            int sw  = (row >> 1) & 3;
            frag_ab af = *(const frag_ab*)&ldsA[buf][row * ROWE + ((quad ^ sw) * 8)];
#pragma unroll
            for (int ni = 0; ni < 4; ++ni)
                acc[mi][ni] = __builtin_amdgcn_mfma_f32_16x16x32_bf16(
                    af, bfrag[ni], acc[mi][ni], 0, 0, 0);
        }

        // stage step ks+1 (loaded a full iteration ago: latency covered);
        // the just-issued ks+2 loads remain in flight across the raw barrier.
        if (ks + 1 < NSTEP) {
            if ((ks & 1) == 0) stageset(pA1, pB1, buf ^ 1);
            else               stageset(pA0, pB0, buf ^ 1);
            BARRIER();
        }
    }

    // ---- epilogue: acc*SCALE + bias + pos[ts[t]][h] ----
    // C/D layout (m89-verified): col = lane&15 (n/h), row = quad*4 + reg (m/t)
#pragma unroll
    for (int mi = 0; mi < 4; ++mi) {
#pragma unroll
        for (int r = 0; r < 4; ++r) {
            int trow = wm + mi * 16 + quad * 4 + r;
            int tsv  = lds_ts[trow];
            const float* prow = pos + (size_t)tsv * H_ + h0;
            size_t orow = ((size_t)b * T_ + (t0 + trow)) * (size_t)H_ + h0;
#pragma unroll
            for (int ni = 0; ni < 4; ++ni) {
                int col = wn + ni * 16 + m_;
                out[orow + col] = acc[mi][ni][r] * SCALE_ + bias + prow[col];
            }
        }
    }
}

extern "C" void kernel_launch(void* const* d_in, const int* in_sizes, int n_in,
                              void* d_out, int out_size, void* d_ws, size_t ws_size,
                              hipStream_t stream) {
    const float* features  = (const float*)d_in[0];
    const int*   ts        = (const int*)d_in[1];
    const int*   date_idx  = (const int*)d_in[2];
    const float* spikes    = (const float*)d_in[3];
    const float* sbias     = (const float*)d_in[4];
    const float* pos       = (const float*)d_in[5];
    float*       out       = (float*)d_out;

    dim3 grid(B_ * (T_ / BM) * (H_ / BN));   // 32 * 8 * 8 = 2048
    NeuralEmbeddingLayer_kernel<<<grid, 256, 0, stream>>>(
        features, ts, date_idx, spikes, sbias, pos, out);
}

// Round 2
// 318.812 us; speedup vs baseline: 1.0278x; 1.0278x over previous
//
#include <hip/hip_runtime.h>
#include <stdint.h>

// Problem constants (from reference)
#define B_  32
#define T_  1024
#define C_  512
#define H_  1024
#define SCALE_ 32.0f   // sqrt(1024)

// Tiling
#define BM 128
#define BN 128
#define BK 32
#define ROWE 32              // elems per LDS row, no pad; XOR swizzle for banks
#define NSTEP (C_ / BK)      // 16
#define NTHR 512             // 8 waves: halves per-thread staging + acc footprint

typedef __attribute__((ext_vector_type(8))) short frag_ab;   // 8 bf16 (4 VGPRs)
typedef __attribute__((ext_vector_type(4))) float frag_cd;   // 4 fp32

// Packed f32x2 -> bf16x2 (RNE), single instruction. Non-volatile: scheduler
// may move/CSE it freely (m240: volatile/pinned cvt_pk hurts).
__device__ __forceinline__ uint32_t cvtpk_bf16(float lo, float hi) {
    uint32_t r;
    asm("v_cvt_pk_bf16_f32 %0, %1, %2" : "=v"(r) : "v"(lo), "v"(hi));
    return r;
}

__device__ __forceinline__ void cvt4_store(unsigned short* dst, float4 v) {
    uint2 p;
    p.x = cvtpk_bf16(v.x, v.y);
    p.y = cvtpk_bf16(v.z, v.w);
    *(uint2*)dst = p;   // 8 B aligned
}

// Raw barrier WITHOUT the __syncthreads() vmcnt(0) drain: per-wave LDS drain
// (lgkmcnt) + s_barrier. Global prefetch loads (register-destined, read-only
// data) legitimately stay in flight across it. lgkmcnt(0) covers BOTH the
// frag ds_reads of this step and the ds_writes into the other buffer, so the
// dbuf write-after-read and read-after-write hazards are both fenced.
// "memory" fences stop the compiler migrating LDS ops across the barrier.
#define BARRIER() do { \
    asm volatile("s_waitcnt lgkmcnt(0)" ::: "memory"); \
    __builtin_amdgcn_s_barrier(); \
    asm volatile("" ::: "memory"); \
} while (0)

__global__ __launch_bounds__(NTHR, 4)   // 4 waves/SIMD -> 128-VGPR budget, 2 blocks/CU
void NeuralEmbeddingLayer_kernel(
    const float* __restrict__ features,     // [B,T,C]
    const int*   __restrict__ ts,           // [B,T]
    const int*   __restrict__ date_idx,     // [B]
    const float* __restrict__ spikes,       // [N_DATES,H,C]
    const float* __restrict__ spikes_bias,  // [N_DATES]
    const float* __restrict__ pos,          // [MAX_F,H]
    float*       __restrict__ out)          // [B,T,H]
{
    const int tid = threadIdx.x;
    const int bid = blockIdx.x;

    // XCD-clustered mapping: one XCD gets whole samples (A+B working set fits
    // its private 4 MB L2).
    const int xcd   = bid & 7;
    const int local = bid >> 3;               // 0..255 within this XCD
    const int b     = ((local >> 6) << 3) + xcd;  // 4 samples per XCD
    const int tile  = local & 63;
    const int t0 = (tile >> 3) * BM;
    const int h0 = (tile & 7) * BN;

    const int   date = date_idx[b];
    const float bias = spikes_bias[date];
    const float* A = features + ((size_t)b * T_ + t0) * C_;     // row stride C_
    const float* W = spikes   + ((size_t)date * H_ + h0) * C_;  // row stride C_

    __shared__ __align__(16) unsigned short ldsA[2][BM * ROWE]; // 8 KB each
    __shared__ __align__(16) unsigned short ldsB[2][BM * ROWE];
    __shared__ int lds_ts[BM];

    // ---- static per-thread staging coordinates ----
    // tile: 128 rows x 8 float4-groups = 1024 groups; 512 threads -> 2 each,
    // rows r0 and r0+64. Swizzle term invariant in i (64 ≡ 0 mod 4 on (row>>1)&3).
    const int r0  = tid >> 3;            // 0..63
    const int c4  = (tid & 7) * 4;       // k offset in floats
    const int jj  = tid & 7;
    const int sw0 = (jj >> 1) ^ ((r0 >> 1) & 3);
    const int offBase = r0 * ROWE + sw0 * 8 + (jj & 1) * 4;

    // Two prefetch register sets (16 VGPRs each): set parity = K-step parity.
    float4 pA0[2], pB0[2], pA1[2], pB1[2];

    auto loadset = [&](float4 (&a)[2], float4 (&w)[2], int k0) {
#pragma unroll
        for (int i = 0; i < 2; ++i) {
            a[i] = *(const float4*)(A + (size_t)(r0 + 64 * i) * C_ + (k0 + c4));
            w[i] = *(const float4*)(W + (size_t)(r0 + 64 * i) * C_ + (k0 + c4));
        }
    };
    auto stageset = [&](float4 (&a)[2], float4 (&w)[2], int buf) {
#pragma unroll
        for (int i = 0; i < 2; ++i) {
            cvt4_store(&ldsA[buf][offBase + i * (64 * ROWE)], a[i]);
            cvt4_store(&ldsB[buf][offBase + i * (64 * ROWE)], w[i]);
        }
    };

    // ---- prologue: issue steps 0 and 1, stage step 0 ----
    int tsval = 0;
    if (tid < BM) tsval = ts[b * T_ + t0 + tid];
    loadset(pA0, pB0, 0);
    loadset(pA1, pB1, BK);          // stays in flight through the first barrier
    if (tid < BM) lds_ts[tid] = tsval;
    stageset(pA0, pB0, 0);          // vmcnt counted: waits only for set0 (+ts)
    BARRIER();

    // ---- wave/lane decode: 8 waves in 2(M) x 4(N), per-wave 64x32 tile ----
    const int wave = tid >> 6;        // 0..7
    const int lane = tid & 63;
    const int quad = lane >> 4;       // k-halfgroup for A/B frags; row-quad for C/D
    const int m_   = lane & 15;
    const int wm = (wave >> 2) * 64;  // 0 or 64  (M / t)
    const int wn = (wave & 3) * 32;   // 0,32,64,96  (N / h)

    frag_cd acc[4][2] = {};           // 32 regs (was 64)

    // ---- K loop: dbuf LDS, distance-2 register prefetch, raw barriers ----
    // Invariant at top of iter ks: LDS buf[ks&1] holds step ks;
    // set[(ks+1)&1] holds step ks+1 (in flight or arrived); set[ks&1] free.
#pragma unroll
    for (int ks = 0; ks < NSTEP; ++ks) {
        const int buf = ks & 1;

        // issue loads for step ks+2 into the freed set (parity ks&1)
        if (ks + 2 < NSTEP) {
            if ((ks & 1) == 0) loadset(pA0, pB0, (ks + 2) * BK);
            else               loadset(pA1, pB1, (ks + 2) * BK);
        }

        // B fragments up front (2); A fragments rolled into the MFMA loop to
        // cap fragment liveness under the (512,4) 128-reg budget.
        frag_ab bfrag[2];
#pragma unroll
        for (int ni = 0; ni < 2; ++ni) {
            int row = wn + ni * 16 + m_;
            int sw  = (row >> 1) & 3;
            bfrag[ni] = *(const frag_ab*)&ldsB[buf][row * ROWE + ((quad ^ sw) * 8)];
        }
#pragma unroll
        for (int mi = 0; mi < 4; ++mi) {
            int row = wm + mi * 16 + m_;
            int sw  = (row >> 1) & 3;
            frag_ab af = *(const frag_ab*)&ldsA[buf][row * ROWE + ((quad ^ sw) * 8)];
#pragma unroll
            for (int ni = 0; ni < 2; ++ni)
                acc[mi][ni] = __builtin_amdgcn_mfma_f32_16x16x32_bf16(
                    af, bfrag[ni], acc[mi][ni], 0, 0, 0);
        }

        // stage step ks+1 (loaded a full iteration ago: latency covered);
        // the just-issued ks+2 loads remain in flight across the raw barrier.
        if (ks + 1 < NSTEP) {
            if ((ks & 1) == 0) stageset(pA1, pB1, buf ^ 1);
            else               stageset(pA0, pB0, buf ^ 1);
            BARRIER();
        }
    }

    // ---- epilogue: acc*SCALE + bias + pos[ts[t]][h] ----
    // C/D layout (m89-verified): col = lane&15 (n/h), row = quad*4 + reg (m/t)
#pragma unroll
    for (int mi = 0; mi < 4; ++mi) {
#pragma unroll
        for (int r = 0; r < 4; ++r) {
            int trow = wm + mi * 16 + quad * 4 + r;
            int tsv  = lds_ts[trow];
            const float* prow = pos + (size_t)tsv * H_ + h0;
            size_t orow = ((size_t)b * T_ + (t0 + trow)) * (size_t)H_ + h0;
#pragma unroll
            for (int ni = 0; ni < 2; ++ni) {
                int col = wn + ni * 16 + m_;
                out[orow + col] = acc[mi][ni][r] * SCALE_ + bias + prow[col];
            }
        }
    }
}

extern "C" void kernel_launch(void* const* d_in, const int* in_sizes, int n_in,
                              void* d_out, int out_size, void* d_ws, size_t ws_size,
                              hipStream_t stream) {
    const float* features  = (const float*)d_in[0];
    const int*   ts        = (const int*)d_in[1];
    const int*   date_idx  = (const int*)d_in[2];
    const float* spikes    = (const float*)d_in[3];
    const float* sbias     = (const float*)d_in[4];
    const float* pos       = (const float*)d_in[5];
    float*       out       = (float*)d_out;

    dim3 grid(B_ * (T_ / BM) * (H_ / BN));   // 32 * 8 * 8 = 2048
    NeuralEmbeddingLayer_kernel<<<grid, NTHR, 0, stream>>>(
        features, ts, date_idx, spikes, sbias, pos, out);
}